// Round 7
// baseline (125.820 us; speedup 1.0000x reference)
//
#include <hip/hip_runtime.h>

// input_tensor: [8,128,128,128,1] fp32 ; random_u: [8,8,3] fp32 ; SCALE=0.2
#define NB   8
#define NS   128
#define VOX  (NS*NS*NS)

// Tile 32w x 8h x 8d. Affine coeff bounds (A^T A = 8I closed form):
//   t_diag in [0.8,1.0], |t_offdiag| <= 0.1, |t_trans| <= 0.1.
// Pixel spans over tile offsets (kd<=7, kh<=7, kw<=31):
//   p0/p1 span <= 7*1 + 7*0.1 + 31*0.1 = 10.8 -> floor-index span <= 11
//     -> taps need rows [i0mn, i0mx+1]: Sd = span+2 <= 13
//   p2 span <= 32.4 -> floor span <= 33 -> cols [i2mn, i2mx+1] <= 35
//     -> +3 alignment loss (ws = i2mn & ~3) -> 38 <= ROW_W = 40
// ZERO-PADDED WINDOW: the window is NOT clamped to the volume. Staging
// chunks outside [0,128) in any dim are written as zeros (ds_write_b128)
// instead of DMA'd; since ws % 4 == 0 and 0/128 are multiples of 4, a 16B
// chunk is always fully-in or fully-out. Taps with v=0 contribute 0 ==
// reference's zero-weight OOB semantics -> ONE uniform compute path.
#define SD    13
#define SH    13
#define ROW_W 40
#define RST   (SH*ROW_W)     // 520, compile-time constant

typedef __attribute__((address_space(1))) const void gconst_t;
typedef __attribute__((address_space(3))) void lds_t;

__global__ __launch_bounds__(256) void warp_resample_kernel(
        const float* __restrict__ img, const float* __restrict__ u,
        float* __restrict__ out) {
    __shared__ float tm[12];
    __shared__ __align__(16) float slab[SD * RST];   // 27,040 B

    const int tid  = threadIdx.x;
    const int bi   = blockIdx.x;
    const int wblk =  bi       & 3;    // 4 w-tiles of 32
    const int hblk = (bi >> 2) & 15;   // 16 h-tiles of 8
    const int dblk = (bi >> 6) & 15;   // 16 d-tiles of 8
    const int b    =  bi >> 10;        // 8 batches

    // ---- affine transform from noise (A^T A = 8I -> closed form), 12 lanes ----
    if (tid < 12) {
        int i = tid >> 2, j = tid & 3;
        float acc = 0.f;
#pragma unroll
        for (int n = 0; n < 8; ++n) {
            float ci = (n & (4 >> i)) ? 1.f : -1.f;
            float cj = (j < 3) ? ((n & (4 >> j)) ? 1.f : -1.f) : 1.f;
            float s  = 0.8f + 0.2f * u[(b * 8 + n) * 3 + i];
            acc += cj * ci * s;
        }
        tm[tid] = acc * 0.125f;
    }
    __syncthreads();

    const float t00 = tm[0], t01 = tm[1], t02 = tm[2],  t03 = tm[3];
    const float t10 = tm[4], t11 = tm[5], t12 = tm[6],  t13 = tm[7];
    const float t20 = tm[8], t21 = tm[9], t22 = tm[10], t23 = tm[11];

    const int d0 = dblk << 3, h0 = hblk << 3, w0 = wblk << 5;
    const float inv = 2.0f / 127.0f;
    const float x0 = -1.f + d0 * inv, y0 = -1.f + h0 * inv, z0 = -1.f + w0 * inv;
    // pixel coords at tile origin; per-index pixel delta == t (inv*63.5 == 1)
    const float P0 = (t00 * x0 + t01 * y0 + t02 * z0 + t03 + 1.f) * 63.5f;
    const float P1 = (t10 * x0 + t11 * y0 + t12 * z0 + t13 + 1.f) * 63.5f;
    const float P2 = (t20 * x0 + t21 * y0 + t22 * z0 + t23 + 1.f) * 63.5f;

    // tile bounds via corner extremes (kd<=7, kh<=7, kw<=31)
    const float mn0 = P0 + fminf(0.f, 7.f*t00) + fminf(0.f, 7.f*t01) + fminf(0.f, 31.f*t02);
    const float mx0 = P0 + fmaxf(0.f, 7.f*t00) + fmaxf(0.f, 7.f*t01) + fmaxf(0.f, 31.f*t02);
    const float mn1 = P1 + fminf(0.f, 7.f*t10) + fminf(0.f, 7.f*t11) + fminf(0.f, 31.f*t12);
    const float mx1 = P1 + fmaxf(0.f, 7.f*t10) + fmaxf(0.f, 7.f*t11) + fmaxf(0.f, 31.f*t12);
    const float mn2 = P2 + fminf(0.f, 7.f*t20) + fminf(0.f, 7.f*t21) + fminf(0.f, 31.f*t22);
    const float mx2 = P2 + fmaxf(0.f, 7.f*t20) + fmaxf(0.f, 7.f*t21) + fmaxf(0.f, 31.f*t22);

    // UNCLAMPED window origin (may be <0 or >NS-window): zero-fill covers OOB
    const int d_lo = (int)floorf(mn0);
    const int h_lo = (int)floorf(mn1);
    const int ws   = ((int)floorf(mn2)) & ~3;            // 16B-aligned, <= i2mn
    const int Sd   = min((int)floorf(mx0) + 2 - d_lo, SD);
    const int Sh   = min((int)floorf(mx1) + 2 - h_lo, SH);

    const int off = __builtin_amdgcn_readfirstlane(
        -(d_lo * RST + h_lo * ROW_W + ws));

    // ---- stage slab: Sd*Sh rows of ROW_W floats; DMA in-volume chunks,
    //      ds_write_b128 zeros for out-of-volume chunks ----
    // lane-task: hi = tid/10, chunk c = tid%10; LDS float offset = 4*tid, so
    // per-wave DMA base = di*RST + (tid&~63)*4 (HW adds lane*16B).
    {
        const float* gb = img + (size_t)b * VOX;
        const int hi = tid / 10;
        const int c  = tid - hi * 10;
        const int jw = ws + (c << 2);
        const int hrow = h_lo + hi;
        const bool whOK = ((unsigned)jw <= (unsigned)(NS - 4)) &&
                          ((unsigned)hrow < (unsigned)NS);
        const int wvbase = (tid & ~63) << 2;             // floats
        const float4 z4 = make_float4(0.f, 0.f, 0.f, 0.f);
        if (hi < Sh) {
            for (int di = 0; di < Sd; ++di) {
                const int drow = d_lo + di;
                if (whOK && (unsigned)drow < (unsigned)NS) {
                    const float* g = gb + ((drow * NS + hrow) * NS + jw);
                    __builtin_amdgcn_global_load_lds(
                        (gconst_t*)g, (lds_t*)(slab + di * RST + wvbase),
                        16, 0, 0);
                } else {
                    *reinterpret_cast<float4*>(slab + di * RST + (tid << 2)) = z4;
                }
            }
        }
    }
    __syncthreads();

    // ---- compute: lanes dense along w; 8 voxels along d per thread;
    //      single uniform path (zero-padded slab == reference OOB semantics) ----
    const int wl = tid & 31, hh = tid >> 5;
    float q0 = P0 + hh * t01 + wl * t02;
    float q1 = P1 + hh * t11 + wl * t12;
    float q2 = P2 + hh * t21 + wl * t22;

    float res[8];
#pragma unroll
    for (int k = 0; k < 8; ++k) {
        float f0 = floorf(q0), f1 = floorf(q1), f2 = floorf(q2);
        int   i0 = (int)f0,    i1 = (int)f1,    i2 = (int)f2;
        float r0 = q0 - f0,    r1 = q1 - f1,    r2 = q2 - f2;

        int base = i0 * RST + i1 * ROW_W + i2 + off;     // const strides
        float a00 = slab[base],           b00 = slab[base + 1];
        float a01 = slab[base + ROW_W],   b01 = slab[base + ROW_W + 1];
        int base2 = base + RST;
        float a10 = slab[base2],          b10 = slab[base2 + 1];
        float a11 = slab[base2 + ROW_W],  b11 = slab[base2 + ROW_W + 1];

        float e0 = fmaf(r2, b00 - a00, a00);
        float e1 = fmaf(r2, b01 - a01, a01);
        float e2 = fmaf(r2, b10 - a10, a10);
        float e3 = fmaf(r2, b11 - a11, a11);
        float c0 = fmaf(r1, e1 - e0, e0);
        float c1 = fmaf(r1, e3 - e2, e2);
        res[k] = fmaf(r0, c1 - c0, c0);

        q0 += t00; q1 += t10; q2 += t20;
    }

    // stores: wave = 2 h-rows x 32 consecutive w -> coalesced 128B segments
    size_t ob = (((size_t)(b * NS + d0) * NS + (h0 + hh)) * NS) + w0 + wl;
#pragma unroll
    for (int k = 0; k < 8; ++k)
        out[ob + (size_t)k * NS * NS] = res[k];
}

extern "C" void kernel_launch(void* const* d_in, const int* in_sizes, int n_in,
                              void* d_out, int out_size, void* d_ws, size_t ws_size,
                              hipStream_t stream) {
    const float* img = (const float*)d_in[0];   // [8,128,128,128,1] fp32
    const float* u   = (const float*)d_in[1];   // [8,8,3] fp32
    float* out = (float*)d_out;

    int blocks = NB * 16 * 16 * 4;              // 8,192 (4w x 16h x 16d tiles)
    warp_resample_kernel<<<blocks, 256, 0, stream>>>(img, u, out);
}